// Round 8
// baseline (281.313 us; speedup 1.0000x reference)
//
#include <hip/hip_runtime.h>
#include <stdint.h>

// ---------------------------------------------------------------------------
// GroupAttentionLayer: RF=16,STRIDE=16 windows tile the image exactly =>
//   yout = leaky(Q K^T / 16) V  (full dense attention per batch), then BN +
//   spatial softmax (mu/beta cancel; only a_c = g1/sqrt(var+eps) survives).
// B=4, P=4096 px/batch (T=16384 rows), C=256. Inputs fp32, OUTPUT fp32.
// R8: (a) k_attn waves re-partitioned (q-half x 64-key / 64-ch groups):
//     Q/S LDS reads halved, K/V doubling absorbed by L1 (wave pairs share
//     lines); S computed TRANSPOSED (mfma(kf,qv) -> D[key][q]) so writes
//     pack as ds_write_b64; pad 268.
//     (b) k_cvt + k_stats1 folded into k_qkv_gemm: X fp32 staged once per
//     block (1-pass X), frag-major Wt from L2, BN stats in epilogue via
//     shfl_xor + fp32 atomics.
// ---------------------------------------------------------------------------

typedef __attribute__((ext_vector_type(8)))  short short8;   // 8 x bf16
typedef __attribute__((ext_vector_type(4)))  float f32x4;    // 16x16 acc
typedef __attribute__((ext_vector_type(16))) float f32x16;   // 32x32 acc
typedef __attribute__((ext_vector_type(4)))  unsigned short ushort4v;

#define ALPHA 0.3f
#define EPS   1e-3
#define NTOT  16384.0

__device__ __forceinline__ unsigned short f2bf(float f){
  unsigned u = __float_as_uint(f);
  u += 0x7FFFu + ((u>>16)&1u);          // RNE
  return (unsigned short)(u>>16);
}
__device__ __forceinline__ float lrelu(float x){ return x > 0.f ? x : ALPHA*x; }

// --------------------------------------------------------------- W -> frag-major
// Wtf chunk m = cg*512 + ks*64 + lane holds B[n=cg*16+(lane&15)]
//                                         [k=ks*32+(lane>>4)*8+j], j=0..7
__global__ __launch_bounds__(256)
void k_wtrans(const float* __restrict__ Wq,
              const float* __restrict__ Wk,
              const float* __restrict__ Wv,
              unsigned short* __restrict__ Wtf){
  int t = blockIdx.x*256 + threadIdx.x;      // 0..24575
  int cg = t >> 9, r = t & 511;
  int ks = r >> 6, lane = r & 63;
  int col = cg*16 + (lane & 15);
  int proj = col >> 8, d = col & 255;
  const float* W = (proj==0) ? Wq : ((proj==1) ? Wk : Wv);
  int c0 = ks*32 + (lane >> 4)*8;
  unsigned short o[8];
#pragma unroll
  for (int j = 0; j < 8; ++j) o[j] = f2bf(W[(size_t)(c0+j)*256 + d]);
  uint4 u;
  u.x = (unsigned)o[0] | ((unsigned)o[1]<<16);
  u.y = (unsigned)o[2] | ((unsigned)o[3]<<16);
  u.z = (unsigned)o[4] | ((unsigned)o[5]<<16);
  u.w = (unsigned)o[6] | ((unsigned)o[7]<<16);
  *(uint4*)(Wtf + (size_t)t*8) = u;
}

// --------------------------------------------------------------- QKV GEMM
// 256 blocks x 64 rows. X fp32 staged->bf16 LDS once; loops 12 col-tiles;
// Wt frags lane-contiguous from L2. Epilogue: Y write + BN stats atomics.
__global__ __launch_bounds__(256)
void k_qkv_gemm(const float* __restrict__ X,
                const unsigned short* __restrict__ Wtf,
                float* __restrict__ Y, float* __restrict__ stf){
  __shared__ __align__(16) unsigned short At[64*264];
  int tid = threadIdx.x;
  int mb = blockIdx.x;
#pragma unroll
  for (int it = 0; it < 16; ++it){
    int s = it*256 + tid;                 // 0..4095
    int row = s >> 6, c4 = s & 63;
    float4 v = *(const float4*)(X + ((size_t)(mb*64+row))*256 + c4*4);
    ushort4v o; o.x=f2bf(v.x); o.y=f2bf(v.y); o.z=f2bf(v.z); o.w=f2bf(v.w);
    *(ushort4v*)(At + row*264 + c4*4) = o;
  }
  __syncthreads();
  int lane = tid & 63, wv = tid >> 6;
  int ln15 = lane & 15, quad = lane >> 4;
  int rw = (wv & 1)*32, cw = (wv >> 1)*32;
  for (int nb = 0; nb < 12; ++nb){
    f32x4 acc[2][2] = {};
#pragma unroll
    for (int ks = 0; ks < 8; ++ks){
      short8 afr[2], bfr[2];
#pragma unroll
      for (int mt = 0; mt < 2; ++mt)
        afr[mt] = *(const short8*)(At + (rw + mt*16 + ln15)*264 + (ks*4+quad)*8);
#pragma unroll
      for (int nt = 0; nt < 2; ++nt){
        int cg = nb*4 + (wv>>1)*2 + nt;
        bfr[nt] = *(const short8*)(Wtf + ((size_t)(cg*8 + ks))*512 + lane*8);
      }
#pragma unroll
      for (int mt = 0; mt < 2; ++mt)
#pragma unroll
        for (int nt = 0; nt < 2; ++nt)
          acc[mt][nt] = __builtin_amdgcn_mfma_f32_16x16x32_bf16(afr[mt], bfr[nt], acc[mt][nt], 0,0,0);
    }
#pragma unroll
    for (int nt = 0; nt < 2; ++nt){
      float s = 0.f, q = 0.f;
#pragma unroll
      for (int mt = 0; mt < 2; ++mt)
#pragma unroll
        for (int r = 0; r < 4; ++r){
          int row = mb*64 + rw + mt*16 + quad*4 + r;
          int col = nb*64 + cw + nt*16 + ln15;
          float v = acc[mt][nt][r];
          Y[(size_t)row*768 + col] = v;
          s += v; q += v*v;
        }
      s += __shfl_xor(s, 16); s += __shfl_xor(s, 32);
      q += __shfl_xor(q, 16); q += __shfl_xor(q, 32);
      if (lane < 16){
        int col = nb*64 + cw + nt*16 + lane;
        atomicAdd(&stf[col], s);
        atomicAdd(&stf[768 + col], q);
      }
    }
  }
}

// --------------------------------------------------------------- BN coefs
__global__ __launch_bounds__(256)
void k_coef(const float* __restrict__ stf,
            const float* __restrict__ gq, const float* __restrict__ bq,
            const float* __restrict__ gk, const float* __restrict__ bk,
            const float* __restrict__ gv, const float* __restrict__ bv,
            float* __restrict__ scv, float* __restrict__ shv){
  int cc = blockIdx.x*256 + threadIdx.x;   // 0..767
  int proj = cc >> 8, c = cc & 255;
  double mu  = (double)stf[cc]     * (1.0/NTOT);
  double var = (double)stf[768+cc] * (1.0/NTOT) - mu*mu;
  double g = (proj==0) ? gq[c] : (proj==1) ? gk[c] : gv[c];
  double b = (proj==0) ? bq[c] : (proj==1) ? bk[c] : bv[c];
  double sc = g / sqrt(var + EPS);
  scv[cc] = (float)sc;
  shv[cc] = (float)(b - mu*sc);
}

// --------------------------------------------------------------- BN+leaky Q,K
// writes fragment-major Qf/Kf. thread: one row t, one 8-ch chunk of Q or K.
__global__ __launch_bounds__(256)
void k_bn_qk(const float* __restrict__ Y,
             const float* __restrict__ scv, const float* __restrict__ shv,
             unsigned short* __restrict__ Qf, unsigned short* __restrict__ Kf){
  int idx = blockIdx.x*256 + threadIdx.x;
  int t = idx >> 6, cb = idx & 63;
  int proj = cb >> 5, cbl = cb & 31;
  int ch0 = cbl*8;
  const float* src = Y + (size_t)t*768 + proj*256 + ch0;
  float4 v0 = *(const float4*)(src);
  float4 v1 = *(const float4*)(src + 4);
  const float* sc = scv + proj*256 + ch0;
  const float* sh = shv + proj*256 + ch0;
  unsigned short r[8];
  r[0]=f2bf(lrelu(v0.x*sc[0]+sh[0])); r[1]=f2bf(lrelu(v0.y*sc[1]+sh[1]));
  r[2]=f2bf(lrelu(v0.z*sc[2]+sh[2])); r[3]=f2bf(lrelu(v0.w*sc[3]+sh[3]));
  r[4]=f2bf(lrelu(v1.x*sc[4]+sh[4])); r[5]=f2bf(lrelu(v1.y*sc[5]+sh[5]));
  r[6]=f2bf(lrelu(v1.z*sc[6]+sh[6])); r[7]=f2bf(lrelu(v1.w*sc[7]+sh[7]));
  uint4 u;
  u.x = (unsigned)r[0] | ((unsigned)r[1]<<16);
  u.y = (unsigned)r[2] | ((unsigned)r[3]<<16);
  u.z = (unsigned)r[4] | ((unsigned)r[5]<<16);
  u.w = (unsigned)r[6] | ((unsigned)r[7]<<16);
  int g = t >> 5, l31r = t & 31;
  int ks = cbl >> 1, l5c = cbl & 1;
  unsigned short* dst = (proj ? Kf : Qf) + ((size_t)((g*16 + ks)*64 + l5c*32 + l31r))*8;
  *(uint4*)dst = u;
}

// --------------------------------------------------------------- BN+leaky Vf
__global__ __launch_bounds__(256)
void k_bn_v(const float* __restrict__ Y,
            const float* __restrict__ scv, const float* __restrict__ shv,
            unsigned short* __restrict__ Vf){
  __shared__ unsigned short tile[64][66];
  int tid = threadIdx.x;
  int pt = blockIdx.x, ct = blockIdx.y, b = blockIdx.z;
  int cl = tid & 63, rq = tid >> 6;
  int c  = ct*64 + cl;
  float sc = scv[512 + c], sh = shv[512 + c];
#pragma unroll 4
  for (int k = 0; k < 16; ++k){
    int r = k*4 + rq;
    size_t t = (size_t)b*4096 + pt*64 + r;
    float v = Y[t*768 + 512 + c];
    tile[r][cl] = f2bf(lrelu(v*sc + sh));
  }
  __syncthreads();
#pragma unroll
  for (int it = 0; it < 2; ++it){
    int m = it*256 + tid;
    int c2 = m >> 3, kg = m & 7;
    int ch = ct*64 + c2;
    int gc = b*8 + (ch >> 5), l31c = ch & 31;
    int kp = pt*4 + (kg >> 1), l5k = kg & 1;
    unsigned short r0 = tile[kg*8+0][c2], r1 = tile[kg*8+1][c2];
    unsigned short r2 = tile[kg*8+2][c2], r3 = tile[kg*8+3][c2];
    unsigned short r4 = tile[kg*8+4][c2], r5 = tile[kg*8+5][c2];
    unsigned short r6 = tile[kg*8+6][c2], r7 = tile[kg*8+7][c2];
    uint4 u;
    u.x = (unsigned)r0 | ((unsigned)r1<<16);
    u.y = (unsigned)r2 | ((unsigned)r3<<16);
    u.z = (unsigned)r4 | ((unsigned)r5<<16);
    u.w = (unsigned)r6 | ((unsigned)r7<<16);
    *(uint4*)(Vf + ((size_t)((gc*256 + kp)*64 + l5k*32 + l31c))*8) = u;
  }
}

// --------------------------------------------------------------- attention
// 512 blocks x 512 threads. blk&7 = (b,half) XCD-pinned. 8 iters BK=256.
// wave w: qh=w&1 (32-row half), grp=w>>1.
// Phase1: keys grp*64..+64 (2 chains), S^T via mfma(kf,qv) -> b64 S writes.
// Phase2: channels grp*64..+64 (2 chains). Wave pairs share K/V lines (L1).
__global__ __launch_bounds__(512, 4)
void k_attn(const unsigned short* __restrict__ Qf,
            const unsigned short* __restrict__ Kf,
            const unsigned short* __restrict__ Vf,
            float* __restrict__ P0, float* __restrict__ P1){
  __shared__ __align__(16) unsigned short Ql[64*256];   // frag-major Q tile
  __shared__ __align__(16) unsigned short Sl[64*268];   // [q][key] pad 268
  int tid = threadIdx.x;
  int blk = blockIdx.x;
  int qt = blk >> 3, combo = blk & 7;
  int b = combo >> 1, half = combo & 1;
  int q0 = qt*64;
  int lane = tid & 63, w = tid >> 6;
  int l31 = lane & 31, l5 = lane >> 5;
  int qh = w & 1, grp = w >> 1;
  float* P = half ? P1 : P0;

  // stage Q tile (32KB contiguous, frag-major identity)
  {
    const uint4* src = (const uint4*)(Qf + (size_t)(b*128 + qt*2)*8192);
    uint4* dst = (uint4*)Ql;
#pragma unroll
    for (int it = 0; it < 4; ++it) dst[it*512 + tid] = src[it*512 + tid];
  }
  __syncthreads();

  f32x16 acc2[2] = {};
  const unsigned short* kb  = Kf + (size_t)(b*128 + half*64 + grp*2)*8192 + lane*8;
  const unsigned short* vb0 = Vf + ((size_t)((b*8 + grp*2    )*256 + half*128))*512 + lane*8;
  const unsigned short* vb1 = Vf + ((size_t)((b*8 + grp*2 + 1)*256 + half*128))*512 + lane*8;
  const unsigned short* qa  = Ql + (size_t)(qh*16)*512 + lane*8;
  unsigned short* swr = Sl + (qh*32 + l31)*268 + grp*64 + l5*4;

  for (int kt = 0; kt < 8; ++kt){
    // phase 1: S^T[key][q] for keys grp*64..+64, rows qh*32..+32
    f32x16 a1[2] = {};
    const unsigned short* kbt = kb + (size_t)kt*8*8192;
#pragma unroll
    for (int ks = 0; ks < 16; ++ks){
      short8 qv = *(const short8*)(qa + ks*512);
      short8 k0 = *(const short8*)(kbt + ks*512);
      short8 k1 = *(const short8*)(kbt + 8192 + ks*512);
      a1[0] = __builtin_amdgcn_mfma_f32_32x32x16_bf16(k0, qv, a1[0], 0, 0, 0);
      a1[1] = __builtin_amdgcn_mfma_f32_32x32x16_bf16(k1, qv, a1[1], 0, 0, 0);
    }
    __syncthreads();   // B0: all waves done reading Sl of iter kt-1
    // D[key][q]: key-local=(reg&3)+8*(reg>>2)+4*l5, q=l31.
    // 4-reg groups = 4 consecutive keys -> one b64 per group.
#pragma unroll
    for (int kc = 0; kc < 2; ++kc)
#pragma unroll
      for (int rg = 0; rg < 4; ++rg){
        unsigned short p0 = f2bf(lrelu(a1[kc][rg*4+0]*0.0625f));
        unsigned short p1 = f2bf(lrelu(a1[kc][rg*4+1]*0.0625f));
        unsigned short p2 = f2bf(lrelu(a1[kc][rg*4+2]*0.0625f));
        unsigned short p3 = f2bf(lrelu(a1[kc][rg*4+3]*0.0625f));
        uint2 u;
        u.x = (unsigned)p0 | ((unsigned)p1<<16);
        u.y = (unsigned)p2 | ((unsigned)p3<<16);
        *(uint2*)(swr + kc*32 + rg*8) = u;
      }
    __syncthreads();   // B1: S visible
    // phase 2: acc2 += S[32q x 256k] . V^T[64ch x 256k]
    const unsigned short* v0t = vb0 + (size_t)kt*8192;
    const unsigned short* v1t = vb1 + (size_t)kt*8192;
#pragma unroll
    for (int kk = 0; kk < 16; ++kk){
      short8 sf = *(const short8*)(Sl + (qh*32 + l31)*268 + kk*16 + l5*8);
      short8 v0 = *(const short8*)(v0t + kk*512);
      short8 v1 = *(const short8*)(v1t + kk*512);
      acc2[0] = __builtin_amdgcn_mfma_f32_32x32x16_bf16(sf, v0, acc2[0], 0, 0, 0);
      acc2[1] = __builtin_amdgcn_mfma_f32_32x32x16_bf16(sf, v1, acc2[1], 0, 0, 0);
    }
  }
#pragma unroll
  for (int ct = 0; ct < 2; ++ct)
#pragma unroll
    for (int reg = 0; reg < 16; ++reg){
      int row = q0 + qh*32 + (reg & 3) + 8*(reg >> 2) + 4*l5;
      int col = grp*64 + ct*32 + l31;
      P[((size_t)b*4096 + row)*256 + col] = acc2[ct][reg];
    }
}

// ------------------------------------------------- partial reduce + BN stats
__global__ __launch_bounds__(256)
void k_red(const float* __restrict__ P0, const float* __restrict__ P1,
           float* __restrict__ yout, double* __restrict__ std_){
  int tid = threadIdx.x;
  int r0 = blockIdx.x*32;
  double sum = 0, sq = 0;
#pragma unroll 4
  for (int r = 0; r < 32; ++r){
    size_t idx = (size_t)(r0 + r)*256 + tid;
    float v = P0[idx] + P1[idx];
    yout[idx] = v;
    sum += v; sq += (double)v*v;
  }
  atomicAdd(&std_[tid], sum);
  atomicAdd(&std_[256 + tid], sq);
}

// --------------------------------------------------------------- softmax
__global__ __launch_bounds__(256)
void k_soft1(const float* __restrict__ yout, const double* __restrict__ std_,
             const float* __restrict__ g1, float* __restrict__ sums){
  __shared__ float red[256];
  __shared__ float sA[64], sK[64];
  int tid = threadIdx.x;
  int chunk = blockIdx.x, ct = blockIdx.y, b = blockIdx.z;
  int cl = tid & 63, pg = tid >> 6;
  int c = ct*64 + cl;
  if (tid < 64){
    int cc = ct*64 + tid;
    double mu  = std_[cc]*(1.0/NTOT);
    double var = std_[256 + cc]*(1.0/NTOT) - mu*mu;
    double a = g1[cc] / sqrt(var + EPS);
    sA[tid] = (float)a;
    sK[tid] = (float)(a*mu);
  }
  __syncthreads();
  float a = sA[cl], K = sK[cl];
  float s = 0.f;
  const float* base = yout + ((size_t)b*4096 + chunk*256)*256 + c;
#pragma unroll 4
  for (int k = 0; k < 64; ++k){
    float v = base[(size_t)(pg + k*4)*256];
    s += __expf(v*a - K);
  }
  red[tid] = s;
  __syncthreads();
  if (tid < 64){
    float tot = red[tid] + red[64+tid] + red[128+tid] + red[192+tid];
    atomicAdd(&sums[b*256 + ct*64 + tid], tot);
  }
}

__global__ __launch_bounds__(256)
void k_soft2(const float* __restrict__ yout, const double* __restrict__ std_,
             const float* __restrict__ g1, const float* __restrict__ sums,
             float* __restrict__ out){
  __shared__ float sA[64], sK[64], sR[64];
  int tid = threadIdx.x;
  int chunk = blockIdx.x, ct = blockIdx.y, b = blockIdx.z;
  int cl = tid & 63, pg = tid >> 6;
  int c = ct*64 + cl;
  if (tid < 64){
    int cc = ct*64 + tid;
    double mu  = std_[cc]*(1.0/NTOT);
    double var = std_[256 + cc]*(1.0/NTOT) - mu*mu;
    double a = g1[cc] / sqrt(var + EPS);
    sA[tid] = (float)a;
    sK[tid] = (float)(a*mu);
    sR[tid] = 1.f / sums[b*256 + cc];
  }
  __syncthreads();
  float a = sA[cl], K = sK[cl], rl = sR[cl];
  const float* base = yout + ((size_t)b*4096 + chunk*256)*256 + c;
  float* obase = out + ((size_t)b*4096 + chunk*256)*256 + c;
#pragma unroll 4
  for (int k = 0; k < 64; ++k){
    size_t idx = (size_t)(pg + k*4)*256;
    obase[idx] = __expf(base[idx]*a - K) * rl;
  }
}

// ---------------------------------------------------------------------------
extern "C" void kernel_launch(void* const* d_in, const int* in_sizes, int n_in,
                              void* d_out, int out_size, void* d_ws, size_t ws_size,
                              hipStream_t stream){
  (void)in_sizes; (void)n_in; (void)out_size; (void)ws_size;
  const float* X  = (const float*)d_in[0];
  const float* Wq = (const float*)d_in[1];
  const float* gq = (const float*)d_in[2];
  const float* bq = (const float*)d_in[3];
  const float* Wk = (const float*)d_in[4];
  const float* gk = (const float*)d_in[5];
  const float* bk = (const float*)d_in[6];
  const float* Wv = (const float*)d_in[7];
  const float* gv = (const float*)d_in[8];
  const float* bv = (const float*)d_in[9];
  const float* g1 = (const float*)d_in[10];
  // d_in[11] = b1: cancels inside the spatial softmax

  char* ws = (char*)d_ws;
  float*          stf  = (float*)ws;                         // 1536 f32 (Y stats)
  double*         std_ = (double*)(ws + 6144);               // 512 f64 (yout stats)
  float*          sums = (float*)(ws + 10240);               // 1024 f32
  float*          scv  = (float*)(ws + 14336);               // 768 f32
  float*          shv  = (float*)(ws + 17408);               // 768 f32
  unsigned short* Wtf  = (unsigned short*)(ws + 20480);      // frag-major 384KB
  float*          Y    = (float*)(ws + 413696);              // 16384x768 f32 48MB
  unsigned short* Qf   = (unsigned short*)(ws + 50745344);   // frag-major 8MB
  unsigned short* Kf   = (unsigned short*)(ws + 59133952);   // frag-major 8MB
  unsigned short* Vf   = (unsigned short*)(ws + 67522560);   // frag-major 8MB
  // Y dead after bn_v: overlay P0|P1|yout
  float*          P0   = Y;
  float*          P1   = (float*)((char*)Y + 16777216);
  float*          yo   = (float*)((char*)Y + 33554432);

  hipMemsetAsync(ws, 0, 14336, stream);
  k_wtrans  <<<96, 256, 0, stream>>>(Wq, Wk, Wv, Wtf);
  k_qkv_gemm<<<256, 256, 0, stream>>>(X, Wtf, Y, stf);
  k_coef    <<<3, 256, 0, stream>>>(stf, gq, bq, gk, bk, gv, bv, scv, shv);
  k_bn_qk   <<<4096, 256, 0, stream>>>(Y, scv, shv, Qf, Kf);
  k_bn_v    <<<dim3(64,4,4), 256, 0, stream>>>(Y, scv, shv, Vf);
  k_attn    <<<512, 512, 0, stream>>>(Qf, Kf, Vf, P0, P1);
  k_red     <<<512, 256, 0, stream>>>(P0, P1, yo, std_);
  k_soft1   <<<dim3(16,4,4), 256, 0, stream>>>(yo, std_, g1, sums);
  k_soft2   <<<dim3(16,4,4), 256, 0, stream>>>(yo, std_, g1, sums, (float*)d_out);
}

// Round 9
// 258.691 us; speedup vs baseline: 1.0874x; 1.0874x over previous
//
#include <hip/hip_runtime.h>
#include <stdint.h>

// ---------------------------------------------------------------------------
// GroupAttentionLayer: RF=16,STRIDE=16 windows tile the image exactly =>
//   yout = leaky(Q K^T / 16) V  (full dense attention per batch), then BN +
//   spatial softmax (mu/beta cancel; only a_c = g1/sqrt(var+eps) survives).
// B=4, P=4096 px/batch (T=16384 rows), C=256. Inputs fp32, OUTPUT fp32.
// R9: k_attn = R7 wave partition (min VMEM: R8 proved VMEM issues cost more
// than LDS reads) + R8 transposed-S epilogue (b64 S writes, 268 pad).
// Front-end: 768-block fused GEMM (3/CU, stats in epilogue, no k_cvt),
// merged BN-apply kernel.
// ---------------------------------------------------------------------------

typedef __attribute__((ext_vector_type(8)))  short short8;   // 8 x bf16
typedef __attribute__((ext_vector_type(4)))  float f32x4;    // 16x16 acc
typedef __attribute__((ext_vector_type(16))) float f32x16;   // 32x32 acc
typedef __attribute__((ext_vector_type(4)))  unsigned short ushort4v;

#define ALPHA 0.3f
#define EPS   1e-3
#define NTOT  16384.0

__device__ __forceinline__ unsigned short f2bf(float f){
  unsigned u = __float_as_uint(f);
  u += 0x7FFFu + ((u>>16)&1u);          // RNE
  return (unsigned short)(u>>16);
}
__device__ __forceinline__ float lrelu(float x){ return x > 0.f ? x : ALPHA*x; }

// --------------------------------------------------------------- W -> frag-major
// Wtf chunk m = cg*512 + ks*64 + lane holds B[n=cg*16+(lane&15)]
//                                         [k=ks*32+(lane>>4)*8+j], j=0..7
__global__ __launch_bounds__(256)
void k_wtrans(const float* __restrict__ Wq,
              const float* __restrict__ Wk,
              const float* __restrict__ Wv,
              unsigned short* __restrict__ Wtf){
  int t = blockIdx.x*256 + threadIdx.x;      // 0..24575
  int cg = t >> 9, r = t & 511;
  int ks = r >> 6, lane = r & 63;
  int col = cg*16 + (lane & 15);
  int proj = col >> 8, d = col & 255;
  const float* W = (proj==0) ? Wq : ((proj==1) ? Wk : Wv);
  int c0 = ks*32 + (lane >> 4)*8;
  unsigned short o[8];
#pragma unroll
  for (int j = 0; j < 8; ++j) o[j] = f2bf(W[(size_t)(c0+j)*256 + d]);
  uint4 u;
  u.x = (unsigned)o[0] | ((unsigned)o[1]<<16);
  u.y = (unsigned)o[2] | ((unsigned)o[3]<<16);
  u.z = (unsigned)o[4] | ((unsigned)o[5]<<16);
  u.w = (unsigned)o[6] | ((unsigned)o[7]<<16);
  *(uint4*)(Wtf + (size_t)t*8) = u;
}

// --------------------------------------------------------------- QKV GEMM
// grid (256,3): 64 rows x one 256-col projection per block. X fp32 staged
// ->bf16 LDS once per block; Wt frags lane-contiguous from L2; BN stats in
// epilogue (shfl + fp32 atomics). 768 blocks = 3/CU.
__global__ __launch_bounds__(256)
void k_qkv_gemm(const float* __restrict__ X,
                const unsigned short* __restrict__ Wtf,
                float* __restrict__ Y, float* __restrict__ stf){
  __shared__ __align__(16) unsigned short At[64*264];
  int tid = threadIdx.x;
  int mb = blockIdx.x, proj = blockIdx.y;
#pragma unroll
  for (int it = 0; it < 16; ++it){
    int s = it*256 + tid;                 // 0..4095
    int row = s >> 6, c4 = s & 63;
    float4 v = *(const float4*)(X + ((size_t)(mb*64+row))*256 + c4*4);
    ushort4v o; o.x=f2bf(v.x); o.y=f2bf(v.y); o.z=f2bf(v.z); o.w=f2bf(v.w);
    *(ushort4v*)(At + row*264 + c4*4) = o;
  }
  __syncthreads();
  int lane = tid & 63, wv = tid >> 6;
  int ln15 = lane & 15, quad = lane >> 4;
  int rw = (wv & 1)*32, cw = (wv >> 1)*32;
#pragma unroll
  for (int nb = 0; nb < 4; ++nb){
    f32x4 acc[2][2] = {};
#pragma unroll
    for (int ks = 0; ks < 8; ++ks){
      short8 afr[2], bfr[2];
#pragma unroll
      for (int mt = 0; mt < 2; ++mt)
        afr[mt] = *(const short8*)(At + (rw + mt*16 + ln15)*264 + (ks*4+quad)*8);
#pragma unroll
      for (int nt = 0; nt < 2; ++nt){
        int cg = proj*16 + nb*4 + (wv>>1)*2 + nt;
        bfr[nt] = *(const short8*)(Wtf + ((size_t)(cg*8 + ks))*512 + lane*8);
      }
#pragma unroll
      for (int mt = 0; mt < 2; ++mt)
#pragma unroll
        for (int nt = 0; nt < 2; ++nt)
          acc[mt][nt] = __builtin_amdgcn_mfma_f32_16x16x32_bf16(afr[mt], bfr[nt], acc[mt][nt], 0,0,0);
    }
#pragma unroll
    for (int nt = 0; nt < 2; ++nt){
      float s = 0.f, q = 0.f;
      int col = proj*256 + nb*64 + cw + nt*16 + ln15;
#pragma unroll
      for (int mt = 0; mt < 2; ++mt)
#pragma unroll
        for (int r = 0; r < 4; ++r){
          int row = mb*64 + rw + mt*16 + quad*4 + r;
          float v = acc[mt][nt][r];
          Y[(size_t)row*768 + col] = v;
          s += v; q += v*v;
        }
      s += __shfl_xor(s, 16); s += __shfl_xor(s, 32);
      q += __shfl_xor(q, 16); q += __shfl_xor(q, 32);
      if (lane < 16){
        int c2 = proj*256 + nb*64 + cw + nt*16 + lane;
        atomicAdd(&stf[c2], s);
        atomicAdd(&stf[768 + c2], q);
      }
    }
  }
}

// --------------------------------------------------------------- BN coefs
__global__ __launch_bounds__(256)
void k_coef(const float* __restrict__ stf,
            const float* __restrict__ gq, const float* __restrict__ bq,
            const float* __restrict__ gk, const float* __restrict__ bk,
            const float* __restrict__ gv, const float* __restrict__ bv,
            float* __restrict__ scv, float* __restrict__ shv){
  int cc = blockIdx.x*256 + threadIdx.x;   // 0..767
  int proj = cc >> 8, c = cc & 255;
  double mu  = (double)stf[cc]     * (1.0/NTOT);
  double var = (double)stf[768+cc] * (1.0/NTOT) - mu*mu;
  double g = (proj==0) ? gq[c] : (proj==1) ? gk[c] : gv[c];
  double b = (proj==0) ? bq[c] : (proj==1) ? bk[c] : bv[c];
  double sc = g / sqrt(var + EPS);
  scv[cc] = (float)sc;
  shv[cc] = (float)(b - mu*sc);
}

// --------------------------------------------------------------- BN apply
// One pass over Y: Q/K -> frag-major Qf/Kf direct; V -> frag-major Vf via
// LDS transpose. 256 blocks x 64 rows.
__global__ __launch_bounds__(256)
void k_bn(const float* __restrict__ Y,
          const float* __restrict__ scv, const float* __restrict__ shv,
          unsigned short* __restrict__ Qf, unsigned short* __restrict__ Kf,
          unsigned short* __restrict__ Vf){
  __shared__ unsigned short tile[64][66];
  int tid = threadIdx.x;
  int blk = blockIdx.x;
  int t0 = blk*64;
  int b = blk >> 6, ptl = blk & 63;
  // ---- part A: Q,K (16 units of (row, 8-ch chunk) per thread)
#pragma unroll
  for (int u16 = 0; u16 < 16; ++u16){
    int u = u16*256 + tid;                 // 0..4095
    int t = t0 + (u >> 6), cb = u & 63;
    int proj = cb >> 5, cbl = cb & 31;
    int ch0 = cbl*8;
    const float* src = Y + (size_t)t*768 + proj*256 + ch0;
    float4 v0 = *(const float4*)(src);
    float4 v1 = *(const float4*)(src + 4);
    const float* sc = scv + proj*256 + ch0;
    const float* sh = shv + proj*256 + ch0;
    unsigned short r[8];
    r[0]=f2bf(lrelu(v0.x*sc[0]+sh[0])); r[1]=f2bf(lrelu(v0.y*sc[1]+sh[1]));
    r[2]=f2bf(lrelu(v0.z*sc[2]+sh[2])); r[3]=f2bf(lrelu(v0.w*sc[3]+sh[3]));
    r[4]=f2bf(lrelu(v1.x*sc[4]+sh[4])); r[5]=f2bf(lrelu(v1.y*sc[5]+sh[5]));
    r[6]=f2bf(lrelu(v1.z*sc[6]+sh[6])); r[7]=f2bf(lrelu(v1.w*sc[7]+sh[7]));
    uint4 u4;
    u4.x = (unsigned)r[0] | ((unsigned)r[1]<<16);
    u4.y = (unsigned)r[2] | ((unsigned)r[3]<<16);
    u4.z = (unsigned)r[4] | ((unsigned)r[5]<<16);
    u4.w = (unsigned)r[6] | ((unsigned)r[7]<<16);
    int g = t >> 5, l31r = t & 31;
    int ks = cbl >> 1, l5c = cbl & 1;
    unsigned short* dst = (proj ? Kf : Qf) + ((size_t)((g*16 + ks)*64 + l5c*32 + l31r))*8;
    *(uint4*)dst = u4;
  }
  // ---- part B: V transpose, 4 x (64px x 64ch) tiles
  int cl = tid & 63, rq = tid >> 6;
  for (int ct = 0; ct < 4; ++ct){
    __syncthreads();
    int c = ct*64 + cl;
    float sc = scv[512 + c], sh = shv[512 + c];
#pragma unroll 4
    for (int k = 0; k < 16; ++k){
      int r = k*4 + rq;
      float v = Y[(size_t)(t0 + r)*768 + 512 + c];
      tile[r][cl] = f2bf(lrelu(v*sc + sh));
    }
    __syncthreads();
#pragma unroll
    for (int it = 0; it < 2; ++it){
      int m = it*256 + tid;
      int c2 = m >> 3, kg = m & 7;
      int ch = ct*64 + c2;
      int gc = b*8 + (ch >> 5), l31c = ch & 31;
      int kp = ptl*4 + (kg >> 1), l5k = kg & 1;
      unsigned short r0 = tile[kg*8+0][c2], r1 = tile[kg*8+1][c2];
      unsigned short r2 = tile[kg*8+2][c2], r3 = tile[kg*8+3][c2];
      unsigned short r4 = tile[kg*8+4][c2], r5 = tile[kg*8+5][c2];
      unsigned short r6 = tile[kg*8+6][c2], r7 = tile[kg*8+7][c2];
      uint4 u;
      u.x = (unsigned)r0 | ((unsigned)r1<<16);
      u.y = (unsigned)r2 | ((unsigned)r3<<16);
      u.z = (unsigned)r4 | ((unsigned)r5<<16);
      u.w = (unsigned)r6 | ((unsigned)r7<<16);
      *(uint4*)(Vf + ((size_t)((gc*256 + kp)*64 + l5k*32 + l31c))*8) = u;
    }
  }
}

// --------------------------------------------------------------- attention
// 512 blocks x 512 threads. blk&7 = (b,half) XCD-pinned. 8 iters BK=256,
// 2 barriers/iter. R7 wave partition (minimal VMEM): phase1 wave w owns ONE
// 32-key group (2 q-row chains); phase2 wave w owns ONE 32-ch group.
// Phase1 uses mfma(kf,qv) -> S TRANSPOSED in regs -> b64 LDS writes (268 pad).
__global__ __launch_bounds__(512, 4)
void k_attn(const unsigned short* __restrict__ Qf,
            const unsigned short* __restrict__ Kf,
            const unsigned short* __restrict__ Vf,
            float* __restrict__ P0, float* __restrict__ P1){
  __shared__ __align__(16) unsigned short Ql[64*256];   // frag-major Q tile
  __shared__ __align__(16) unsigned short Sl[64*268];   // [q][key] pad 268
  int tid = threadIdx.x;
  int blk = blockIdx.x;
  int qt = blk >> 3, combo = blk & 7;
  int b = combo >> 1, half = combo & 1;
  int q0 = qt*64;
  int lane = tid & 63, w = tid >> 6;
  int l31 = lane & 31, l5 = lane >> 5;
  float* P = half ? P1 : P0;

  // stage Q tile (32KB contiguous, frag-major identity)
  {
    const uint4* src = (const uint4*)(Qf + (size_t)(b*128 + qt*2)*8192);
    uint4* dst = (uint4*)Ql;
#pragma unroll
    for (int it = 0; it < 4; ++it) dst[it*512 + tid] = src[it*512 + tid];
  }
  __syncthreads();

  f32x16 acc2[2] = {};
  const unsigned short* kb  = Kf + (size_t)(b*128 + half*64 + w)*8192 + lane*8;
  const unsigned short* vb  = Vf + ((size_t)((b*8 + w)*256 + half*128))*512 + lane*8;
  const unsigned short* qa0 = Ql + lane*8;            // q rows 0..31, + ks*512
  const unsigned short* qa1 = Ql + 16*512 + lane*8;   // q rows 32..63
  unsigned short* swr = Sl + l31*268 + w*32 + l5*4;   // S^T write base (q=l31)

  for (int kt = 0; kt < 8; ++kt){
    // phase 1: S^T[key=w*32..+32][q] over K=256; 2 independent q-half chains
    f32x16 a1[2] = {};
    const unsigned short* kbt = kb + (size_t)kt*8*8192;
#pragma unroll
    for (int ks = 0; ks < 16; ++ks){
      short8 kf  = *(const short8*)(kbt + ks*512);
      short8 q0v = *(const short8*)(qa0 + ks*512);
      short8 q1v = *(const short8*)(qa1 + ks*512);
      a1[0] = __builtin_amdgcn_mfma_f32_32x32x16_bf16(kf, q0v, a1[0], 0, 0, 0);
      a1[1] = __builtin_amdgcn_mfma_f32_32x32x16_bf16(kf, q1v, a1[1], 0, 0, 0);
    }
    __syncthreads();   // B0: all waves done reading Sl of iter kt-1
    // D[key][q]: key-local=(reg&3)+8*(reg>>2)+4*l5, q=l31.
    // 4-reg groups = 4 consecutive keys -> one b64 per group.
#pragma unroll
    for (int qc = 0; qc < 2; ++qc)
#pragma unroll
      for (int rg = 0; rg < 4; ++rg){
        unsigned short p0 = f2bf(lrelu(a1[qc][rg*4+0]*0.0625f));
        unsigned short p1 = f2bf(lrelu(a1[qc][rg*4+1]*0.0625f));
        unsigned short p2 = f2bf(lrelu(a1[qc][rg*4+2]*0.0625f));
        unsigned short p3 = f2bf(lrelu(a1[qc][rg*4+3]*0.0625f));
        uint2 u;
        u.x = (unsigned)p0 | ((unsigned)p1<<16);
        u.y = (unsigned)p2 | ((unsigned)p3<<16);
        *(uint2*)(swr + qc*32*268 + rg*8) = u;
      }
    __syncthreads();   // B1: S visible
    // phase 2: acc2 += S[64q x 256k] . V^T[32ch x 256k], ch = w*32..+32
    const unsigned short* vbt = vb + (size_t)kt*8192;
#pragma unroll
    for (int kk = 0; kk < 16; ++kk){
      short8 vf = *(const short8*)(vbt + kk*512);
      short8 s0 = *(const short8*)(Sl + (     l31)*268 + kk*16 + l5*8);
      short8 s1 = *(const short8*)(Sl + (32 + l31)*268 + kk*16 + l5*8);
      acc2[0] = __builtin_amdgcn_mfma_f32_32x32x16_bf16(s0, vf, acc2[0], 0, 0, 0);
      acc2[1] = __builtin_amdgcn_mfma_f32_32x32x16_bf16(s1, vf, acc2[1], 0, 0, 0);
    }
  }
#pragma unroll
  for (int qc = 0; qc < 2; ++qc)
#pragma unroll
    for (int reg = 0; reg < 16; ++reg){
      int row = q0 + qc*32 + (reg & 3) + 8*(reg >> 2) + 4*l5;
      P[((size_t)b*4096 + row)*256 + w*32 + l31] = acc2[qc][reg];
    }
}

// ------------------------------------------------- partial reduce + BN stats
__global__ __launch_bounds__(256)
void k_red(const float* __restrict__ P0, const float* __restrict__ P1,
           float* __restrict__ yout, double* __restrict__ std_){
  int tid = threadIdx.x;
  int r0 = blockIdx.x*32;
  double sum = 0, sq = 0;
#pragma unroll 4
  for (int r = 0; r < 32; ++r){
    size_t idx = (size_t)(r0 + r)*256 + tid;
    float v = P0[idx] + P1[idx];
    yout[idx] = v;
    sum += v; sq += (double)v*v;
  }
  atomicAdd(&std_[tid], sum);
  atomicAdd(&std_[256 + tid], sq);
}

// --------------------------------------------------------------- softmax
__global__ __launch_bounds__(256)
void k_soft1(const float* __restrict__ yout, const double* __restrict__ std_,
             const float* __restrict__ g1, float* __restrict__ sums){
  __shared__ float red[256];
  __shared__ float sA[64], sK[64];
  int tid = threadIdx.x;
  int chunk = blockIdx.x, ct = blockIdx.y, b = blockIdx.z;
  int cl = tid & 63, pg = tid >> 6;
  int c = ct*64 + cl;
  if (tid < 64){
    int cc = ct*64 + tid;
    double mu  = std_[cc]*(1.0/NTOT);
    double var = std_[256 + cc]*(1.0/NTOT) - mu*mu;
    double a = g1[cc] / sqrt(var + EPS);
    sA[tid] = (float)a;
    sK[tid] = (float)(a*mu);
  }
  __syncthreads();
  float a = sA[cl], K = sK[cl];
  float s = 0.f;
  const float* base = yout + ((size_t)b*4096 + chunk*256)*256 + c;
#pragma unroll 4
  for (int k = 0; k < 64; ++k){
    float v = base[(size_t)(pg + k*4)*256];
    s += __expf(v*a - K);
  }
  red[tid] = s;
  __syncthreads();
  if (tid < 64){
    float tot = red[tid] + red[64+tid] + red[128+tid] + red[192+tid];
    atomicAdd(&sums[b*256 + ct*64 + tid], tot);
  }
}

__global__ __launch_bounds__(256)
void k_soft2(const float* __restrict__ yout, const double* __restrict__ std_,
             const float* __restrict__ g1, const float* __restrict__ sums,
             float* __restrict__ out){
  __shared__ float sA[64], sK[64], sR[64];
  int tid = threadIdx.x;
  int chunk = blockIdx.x, ct = blockIdx.y, b = blockIdx.z;
  int cl = tid & 63, pg = tid >> 6;
  int c = ct*64 + cl;
  if (tid < 64){
    int cc = ct*64 + tid;
    double mu  = std_[cc]*(1.0/NTOT);
    double var = std_[256 + cc]*(1.0/NTOT) - mu*mu;
    double a = g1[cc] / sqrt(var + EPS);
    sA[tid] = (float)a;
    sK[tid] = (float)(a*mu);
    sR[tid] = 1.f / sums[b*256 + cc];
  }
  __syncthreads();
  float a = sA[cl], K = sK[cl], rl = sR[cl];
  const float* base = yout + ((size_t)b*4096 + chunk*256)*256 + c;
  float* obase = out + ((size_t)b*4096 + chunk*256)*256 + c;
#pragma unroll 4
  for (int k = 0; k < 64; ++k){
    size_t idx = (size_t)(pg + k*4)*256;
    obase[idx] = __expf(base[idx]*a - K) * rl;
  }
}

// ---------------------------------------------------------------------------
extern "C" void kernel_launch(void* const* d_in, const int* in_sizes, int n_in,
                              void* d_out, int out_size, void* d_ws, size_t ws_size,
                              hipStream_t stream){
  (void)in_sizes; (void)n_in; (void)out_size; (void)ws_size;
  const float* X  = (const float*)d_in[0];
  const float* Wq = (const float*)d_in[1];
  const float* gq = (const float*)d_in[2];
  const float* bq = (const float*)d_in[3];
  const float* Wk = (const float*)d_in[4];
  const float* gk = (const float*)d_in[5];
  const float* bk = (const float*)d_in[6];
  const float* Wv = (const float*)d_in[7];
  const float* gv = (const float*)d_in[8];
  const float* bv = (const float*)d_in[9];
  const float* g1 = (const float*)d_in[10];
  // d_in[11] = b1: cancels inside the spatial softmax

  char* ws = (char*)d_ws;
  float*          stf  = (float*)ws;                         // 1536 f32 (Y stats)
  double*         std_ = (double*)(ws + 6144);               // 512 f64 (yout stats)
  float*          sums = (float*)(ws + 10240);               // 1024 f32
  float*          scv  = (float*)(ws + 14336);               // 768 f32
  float*          shv  = (float*)(ws + 17408);               // 768 f32
  unsigned short* Wtf  = (unsigned short*)(ws + 20480);      // frag-major 384KB
  float*          Y    = (float*)(ws + 413696);              // 16384x768 f32 48MB
  unsigned short* Qf   = (unsigned short*)(ws + 50745344);   // frag-major 8MB
  unsigned short* Kf   = (unsigned short*)(ws + 59133952);   // frag-major 8MB
  unsigned short* Vf   = (unsigned short*)(ws + 67522560);   // frag-major 8MB
  // Y dead after k_bn: overlay P0|P1|yout
  float*          P0   = Y;
  float*          P1   = (float*)((char*)Y + 16777216);
  float*          yo   = (float*)((char*)Y + 33554432);

  hipMemsetAsync(ws, 0, 14336, stream);
  k_wtrans  <<<96, 256, 0, stream>>>(Wq, Wk, Wv, Wtf);
  k_qkv_gemm<<<dim3(256,3), 256, 0, stream>>>(X, Wtf, Y, stf);
  k_coef    <<<3, 256, 0, stream>>>(stf, gq, bq, gk, bk, gv, bv, scv, shv);
  k_bn      <<<256, 256, 0, stream>>>(Y, scv, shv, Qf, Kf, Vf);
  k_attn    <<<512, 512, 0, stream>>>(Qf, Kf, Vf, P0, P1);
  k_red     <<<512, 256, 0, stream>>>(P0, P1, yo, std_);
  k_soft1   <<<dim3(16,4,4), 256, 0, stream>>>(yo, std_, g1, sums);
  k_soft2   <<<dim3(16,4,4), 256, 0, stream>>>(yo, std_, g1, sums, (float*)d_out);
}